// Round 6
// baseline (169.548 us; speedup 1.0000x reference)
//
#include <hip/hip_runtime.h>
#include <math.h>

#define ALPHA 32.0f
#define MRG 0.1f
#define STAT_WEIGHT 0.01f
#define STAT_ADJ_W 0.15f
#define COS_EPS 1e-8f

typedef __attribute__((ext_vector_type(8))) short bf16x8;
typedef __attribute__((ext_vector_type(4))) float f32x4;
typedef __attribute__((ext_vector_type(4))) unsigned int u32x4;

__device__ __forceinline__ ushort f2bf(float f) {
    unsigned u = __float_as_uint(f);
    return (ushort)((u + 0x7FFFu + ((u >> 16) & 1u)) >> 16);   // RNE
}
__device__ __forceinline__ unsigned pk2(float a, float b) {
    return (unsigned)f2bf(a) | ((unsigned)f2bf(b) << 16);
}

// block-wide (128 threads = 2 waves) sum reduce, result broadcast to all
__device__ __forceinline__ float bred128(float v, float* sm, int d) {
    #pragma unroll
    for (int off = 1; off < 64; off <<= 1) v += __shfl_xor(v, off);
    if ((d & 63) == 0) sm[d >> 6] = v;
    __syncthreads();
    float r = sm[0] + sm[1];
    __syncthreads();
    return r;
}

// ---------------- K1: workspace zero + per-sample stats --------------------
// Grid-stride-zeroes Psum/Nsum/scal/done at entry (kills the memset dispatch;
// safe: only later in-stream dispatches read them). Then the R4-proven body:
// parallel membership scan, owner block computes class stats ascending-j,
// swizzled Xn16 row store. n_valid moved to k_main's finish (Psum[c] > 0).
__global__ void k_stats(const float* __restrict__ X, const float* __restrict__ proxies,
                        const float* __restrict__ cc, const int* __restrict__ T,
                        ushort* __restrict__ Xn16, float* __restrict__ adj,
                        float* __restrict__ zbase, int nzero, int B) {
    const int b = blockIdx.x, d = threadIdx.x;   // d in [0,128) == dim index
    __shared__ int Tl[512];
    __shared__ float sm[2];
    __shared__ int mlist[512];
    __shared__ int mcnt;

    // zero Psum/Nsum/scal/done (consumed only by the NEXT dispatch)
    for (int i = b * 128 + d; i < nzero; i += B * 128) zbase[i] = 0.f;

    for (int i = d; i < B; i += 128) Tl[i] = T[i];
    if (d == 0) mcnt = 0;
    __syncthreads();
    const int c = Tl[b];

    // own row: normalize + swizzled bf16 store
    float x = X[(size_t)b * 128 + d];
    float n2 = bred128(x * x, sm, d);
    float xn = x * rsqrtf(n2 + 1e-12f);
    const int pk = ((((d >> 3) ^ (b & 15)) << 3) | (d & 7));   // swizzled column
    Xn16[(size_t)b * 128 + pk] = f2bf(xn);

    // parallel membership scan
    for (int j = d; j < B; j += 128)
        if (Tl[j] == c) mlist[atomicAdd(&mcnt, 1)] = j;
    __syncthreads();
    const int cnt = mcnt;
    int minj = mlist[0];
    for (int i = 1; i < cnt; ++i) minj = min(minj, mlist[i]);
    if (minj != b) return;                       // earlier block owns this class

    // member stats in ascending-j order (deterministic)
    float sd = 0.f, qd = 0.f;
    int prev = -1;
    for (int rank = 0; rank < cnt; ++rank) {
        int cur = 0x7fffffff;
        for (int i = 0; i < cnt; ++i) { int v = mlist[i]; if (v > prev && v < cur) cur = v; }
        prev = cur;
        float xj = X[(size_t)cur * 128 + d];
        float nj = bred128(xj * xj, sm, d);
        float xnj = xj * rsqrtf(nj + 1e-12f);
        sd += xnj; qd += xnj * xnj;
    }
    float fc = (float)cnt;
    float m = sd / fc;
    float var = fminf(fmaxf(qd / fc - m * m, 1e-6f), 10.0f);
    float sv = bred128(var, sm, d);

    float p  = proxies[(size_t)c * 128 + d];
    float cv = cc[(size_t)c * 128 + d];
    float s2 = bred128(p * p, sm, d);
    float c2 = bred128(cv * cv, sm, d);
    float pc = bred128(p * cv, sm, d);
    if (d == 0) {
        float inv = rsqrtf(s2 + 1e-12f);
        float pn = fmaxf(sqrtf(s2) * inv, COS_EPS);
        float cn = fmaxf(sqrtf(c2), COS_EPS);
        float censim = (pc * inv) / (pn * cn);
        float vw = 1.0f / (1.0f + sv * (1.0f / 128.0f));
        adj[c] = censim * vw * STAT_ADJ_W;
    }
}

// ---------------- K2: row-split GEMM + fused per-slice finish ----------------
// R4-proven body (391 x 2 grid, 128 classes/block, 4-chunk double-buffered LDS
// staging). New: after a block's Psum/Nsum/cabs atomics complete (barrier
// drains them), it bumps done[c0blk]; the SECOND half to finish finalizes its
// own 128 classes (log1p + adj + n_valid) reading totals via atomicAdd(p,0.f)
// for device-scope coherence (G16). The 391st finisher assembles out[0].
// Exactly 2 contributors per class -> FP-deterministic totals (a+b == b+a).
__launch_bounds__(256, 2)
__global__ void k_main(const float* __restrict__ proxies, const float* __restrict__ cc,
                       const ushort* __restrict__ Xsw, const int* __restrict__ T,
                       float* __restrict__ Psum, float* __restrict__ Nsum,
                       const float* __restrict__ adj, unsigned* __restrict__ done,
                       float* __restrict__ scal, float* __restrict__ out,
                       int C, int nblk) {
    const int tid = threadIdx.x, lane = tid & 63, wv = tid >> 6;
    const int nlo = lane & 15, quad = lane >> 4;
    const int c0 = blockIdx.x * 128;
    const int half = blockIdx.y;                  // 0/1: which 256-row half
    const int r0 = half * 256;

    __shared__ ushort Sx[16384];      // 2 x 16 KB double buffer
    __shared__ alignas(16) int Tl[256];
    __shared__ float red[4];
    __shared__ float red3[4][3];
    __shared__ unsigned dflag;
    Tl[tid] = T[r0 + tid];

    // ---- cc |.| partial for this block's 128-class slice (half 0 only) ----
    float cabs = 0.f;
    if (half == 0) {
        const int n4 = ((c0 + 128 <= C) ? 128 : (C - c0)) * 32;
        const float4* cp = (const float4*)(cc + (size_t)c0 * 128);
        #pragma unroll 4
        for (int i = tid; i < n4; i += 256) {
            float4 v = cp[i];
            cabs += fabsf(v.x) + fabsf(v.y) + fabsf(v.z) + fabsf(v.w);
        }
    }

    // ---- B fragments: 2 class-tiles, normalized in-register (proven shape) ----
    const int cls0 = c0 + wv * 32 + nlo;
    const int cls1 = cls0 + 16;
    bf16x8 bfr[2][4];
    #pragma unroll
    for (int t = 0; t < 2; ++t) {
        int cls = c0 + wv * 32 + t * 16 + nlo;
        int cl = (cls < C) ? cls : C - 1;
        const float4* pr = (const float4*)(proxies + (size_t)cl * 128);
        float4 v0[4], v1[4];
        float s2 = 0.f;
        #pragma unroll
        for (int ks = 0; ks < 4; ++ks) {
            v0[ks] = pr[ks * 8 + quad * 2];
            v1[ks] = pr[ks * 8 + quad * 2 + 1];
            s2 += v0[ks].x*v0[ks].x + v0[ks].y*v0[ks].y + v0[ks].z*v0[ks].z + v0[ks].w*v0[ks].w
                + v1[ks].x*v1[ks].x + v1[ks].y*v1[ks].y + v1[ks].z*v1[ks].z + v1[ks].w*v1[ks].w;
        }
        s2 += __shfl_xor(s2, 16);
        s2 += __shfl_xor(s2, 32);
        float pin = rsqrtf(s2 + 1e-12f);
        #pragma unroll
        for (int ks = 0; ks < 4; ++ks) {
            u32x4 u;
            u.x = pk2(v0[ks].x * pin, v0[ks].y * pin);
            u.y = pk2(v0[ks].z * pin, v0[ks].w * pin);
            u.z = pk2(v1[ks].x * pin, v1[ks].y * pin);
            u.w = pk2(v1[ks].z * pin, v1[ks].w * pin);
            bfr[t][ks] = __builtin_bit_cast(bf16x8, u);
        }
    }

    // ---- fragment LDS offsets (in ushorts); swizzle index is nlo ----
    int fro[4];
    #pragma unroll
    for (int ks = 0; ks < 4; ++ks)
        fro[ks] = nlo * 128 + (((ks * 4 + quad) ^ nlo) << 3);

    // ---- staging pipeline: 4 chunks x 64 rows = 16 KB = 1024 uint4 each ----
    const uint4* gX = (const uint4*)Xsw + half * 4096;
    uint4 s0, s1, s2v, s3;
    #define LOADV(ch) { const uint4* p_ = gX + (ch) * 1024 + tid; \
                        s0 = p_[0]; s1 = p_[256]; s2v = p_[512]; s3 = p_[768]; }
    #define WRITEV(bi) { uint4* q_ = (uint4*)&Sx[(bi) * 8192]; \
                         q_[tid] = s0; q_[tid + 256] = s1; q_[tid + 512] = s2v; q_[tid + 768] = s3; }
    LOADV(0); WRITEV(0); LOADV(1);
    __syncthreads();

    float pp0 = 0.f, np0 = 0.f, pp1 = 0.f, np1 = 0.f;
    for (int chunk = 0; chunk < 4; ++chunk) {
        const int bo = (chunk & 1) * 8192;
        if (chunk < 3) {
            WRITEV((chunk + 1) & 1);          // stage next (regs loaded last epoch)
            if (chunk < 2) LOADV(chunk + 2);  // issue loads for chunk+2 now
        }
        #pragma unroll
        for (int rt = 0; rt < 4; ++rt) {
            const ushort* sb = &Sx[bo + rt * 2048];
            bf16x8 a0 = *(const bf16x8*)&sb[fro[0]];
            bf16x8 a1 = *(const bf16x8*)&sb[fro[1]];
            bf16x8 a2 = *(const bf16x8*)&sb[fro[2]];
            bf16x8 a3 = *(const bf16x8*)&sb[fro[3]];
            f32x4 acc0 = {0.f,0.f,0.f,0.f}, acc1 = {0.f,0.f,0.f,0.f};
            acc0 = __builtin_amdgcn_mfma_f32_16x16x32_bf16(a0, bfr[0][0], acc0, 0, 0, 0);
            acc1 = __builtin_amdgcn_mfma_f32_16x16x32_bf16(a0, bfr[1][0], acc1, 0, 0, 0);
            acc0 = __builtin_amdgcn_mfma_f32_16x16x32_bf16(a1, bfr[0][1], acc0, 0, 0, 0);
            acc1 = __builtin_amdgcn_mfma_f32_16x16x32_bf16(a1, bfr[1][1], acc1, 0, 0, 0);
            acc0 = __builtin_amdgcn_mfma_f32_16x16x32_bf16(a2, bfr[0][2], acc0, 0, 0, 0);
            acc1 = __builtin_amdgcn_mfma_f32_16x16x32_bf16(a2, bfr[1][2], acc1, 0, 0, 0);
            acc0 = __builtin_amdgcn_mfma_f32_16x16x32_bf16(a3, bfr[0][3], acc0, 0, 0, 0);
            acc1 = __builtin_amdgcn_mfma_f32_16x16x32_bf16(a3, bfr[1][3], acc1, 0, 0, 0);

            int4 t4 = *(const int4*)&Tl[chunk * 64 + rt * 16 + quad * 4];
            int tvs[4] = {t4.x, t4.y, t4.z, t4.w};
            #pragma unroll
            for (int r = 0; r < 4; ++r) {
                { bool po = (tvs[r] == cls0); float v = acc0[r];
                  float e = __expf(po ? -ALPHA * (v - MRG) : ALPHA * (v + MRG));
                  pp0 += po ? e : 0.f; np0 += po ? 0.f : e; }
                { bool po = (tvs[r] == cls1); float v = acc1[r];
                  float e = __expf(po ? -ALPHA * (v - MRG) : ALPHA * (v + MRG));
                  pp1 += po ? e : 0.f; np1 += po ? 0.f : e; }
            }
        }
        __syncthreads();
    }
    #undef LOADV
    #undef WRITEV

    // ---- per-class half-totals across quads -> global atomics ----
    pp0 += __shfl_xor(pp0, 16); pp0 += __shfl_xor(pp0, 32);
    np0 += __shfl_xor(np0, 16); np0 += __shfl_xor(np0, 32);
    pp1 += __shfl_xor(pp1, 16); pp1 += __shfl_xor(pp1, 32);
    np1 += __shfl_xor(np1, 16); np1 += __shfl_xor(np1, 32);
    if (quad == 0) {
        if (cls0 < C) { atomicAdd(&Psum[cls0], pp0); atomicAdd(&Nsum[cls0], np0); }
        if (cls1 < C) { atomicAdd(&Psum[cls1], pp1); atomicAdd(&Nsum[cls1], np1); }
    }

    // ---- cabs block reduce (half 0 only) ----
    if (half == 0) {
        #pragma unroll
        for (int off = 1; off < 64; off <<= 1) cabs += __shfl_xor(cabs, off);
        if (lane == 0) red[wv] = cabs;
        __syncthreads();
        if (tid == 0) atomicAdd(&scal[2], red[0] + red[1] + red[2] + red[3]);
    }

    // ---- fused finish: second half to complete this c0-slice finalizes it ----
    __syncthreads();                 // drains all waves' outstanding atomics
    __threadfence();
    if (tid == 0) dflag = atomicAdd(&done[blockIdx.x], 1u);
    __syncthreads();
    if (dflag != 1u) return;         // first half out; second half finishes

    const int c = c0 + tid;          // tid<128: one class each
    float lp = 0.f, ln = 0.f, nv = 0.f;
    if (tid < 128 && c < C) {
        float p = atomicAdd(&Psum[c], 0.f);      // coherent read (cross-XCD safe)
        float n = atomicAdd(&Nsum[c], 0.f);
        float a = 0.f;
        if (p > 0.f) { a = adj[c]; nv = 1.f; }   // has_samples <=> p > 0
        lp = log1pf(p * __expf(-ALPHA * a));
        ln = log1pf(n * __expf( ALPHA * a));
    }
    #pragma unroll
    for (int off = 1; off < 64; off <<= 1) {
        lp += __shfl_xor(lp, off);
        ln += __shfl_xor(ln, off);
        nv += __shfl_xor(nv, off);
    }
    if (lane == 0) { red3[wv][0] = lp; red3[wv][1] = ln; red3[wv][2] = nv; }
    __syncthreads();
    if (tid == 0) {
        atomicAdd(&scal[0], red3[0][0] + red3[1][0] + red3[2][0] + red3[3][0]);
        atomicAdd(&scal[1], red3[0][1] + red3[1][1] + red3[2][1] + red3[3][1]);
        atomicAdd(&scal[3], red3[0][2] + red3[1][2] + red3[2][2] + red3[3][2]);
        __threadfence();
        unsigned old = atomicAdd((unsigned*)(scal + 4), 1u);
        if (old == (unsigned)(nblk - 1)) {       // last finisher assembles out
            float S0 = atomicAdd(&scal[0], 0.f);
            float S1 = atomicAdd(&scal[1], 0.f);
            float S2 = atomicAdd(&scal[2], 0.f);
            float S3 = atomicAdd(&scal[3], 0.f);
            out[0] = S0 / S3 + S1 / (float)C + STAT_WEIGHT * (S2 / ((float)C * 128.f));
        }
    }
}

extern "C" void kernel_launch(void* const* d_in, const int* in_sizes, int n_in,
                              void* d_out, int out_size, void* d_ws, size_t ws_size,
                              hipStream_t stream) {
    const float* X       = (const float*)d_in[0];
    const int*   T       = (const int*)d_in[1];
    const float* proxies = (const float*)d_in[2];
    const float* cc      = (const float*)d_in[3];
    float* out = (float*)d_out;

    const int B = in_sizes[1];            // 512
    const int D = in_sizes[0] / B;        // 128
    const int C = in_sizes[2] / D;        // 50000

    // workspace: [Psum C][Nsum C][scal 8][done 512u][adj C][Xn16 B*D bf16]
    float*    Psum = (float*)d_ws;
    float*    Nsum = Psum + C;
    float*    scal = Nsum + C;                         // 8
    unsigned* done = (unsigned*)(scal + 8);            // 512
    float*    adj  = (float*)(done + 512);             // C
    ushort*   Xn16 = (ushort*)(adj + C);               // B*D bf16, swizzled

    const int nblk  = (C + 127) / 128;                 // 391
    const int nzero = 2 * C + 8 + 512;                 // Psum+Nsum+scal+done

    k_stats<<<B, 128, 0, stream>>>(X, proxies, cc, T, Xn16, adj, Psum, nzero, B);
    k_main<<<dim3(nblk, 2), 256, 0, stream>>>(proxies, cc, Xn16, T, Psum, Nsum,
                                              adj, done, scal, out, C, nblk);
}

// Round 7
// 131.825 us; speedup vs baseline: 1.2862x; 1.2862x over previous
//
#include <hip/hip_runtime.h>
#include <math.h>

#define ALPHA 32.0f
#define MRG 0.1f
#define STAT_WEIGHT 0.01f
#define STAT_ADJ_W 0.15f
#define COS_EPS 1e-8f

typedef __attribute__((ext_vector_type(8))) short bf16x8;
typedef __attribute__((ext_vector_type(4))) float f32x4;
typedef __attribute__((ext_vector_type(4))) unsigned int u32x4;

__device__ __forceinline__ ushort f2bf(float f) {
    unsigned u = __float_as_uint(f);
    return (ushort)((u + 0x7FFFu + ((u >> 16) & 1u)) >> 16);   // RNE
}
__device__ __forceinline__ unsigned pk2(float a, float b) {
    return (unsigned)f2bf(a) | ((unsigned)f2bf(b) << 16);
}

// block-wide (128 threads = 2 waves) sum reduce, result broadcast to all
__device__ __forceinline__ float bred128(float v, float* sm, int d) {
    #pragma unroll
    for (int off = 1; off < 64; off <<= 1) v += __shfl_xor(v, off);
    if ((d & 63) == 0) sm[d >> 6] = v;
    __syncthreads();
    float r = sm[0] + sm[1];
    __syncthreads();
    return r;
}

// ---------------- K1: ws zero + cc |.| scan + per-sample stats ---------------
// Zeroes the Psum region (consumed only by later in-stream dispatches; no
// fence needed). Streams cc for the |.| partial -> cabs_part[b] (plain store,
// no atomic). Then the proven stats body: parallel membership scan, owner
// block computes class stats ascending-j, swizzled Xn16 row store.
__global__ void k_stats(const float* __restrict__ X, const float* __restrict__ proxies,
                        const float* __restrict__ cc, const int* __restrict__ T,
                        ushort* __restrict__ Xn16, float* __restrict__ adj,
                        float* __restrict__ zbase, int nzero,
                        float* __restrict__ cabs_part, int C, int B) {
    const int b = blockIdx.x, d = threadIdx.x;   // d in [0,128) == dim index
    __shared__ int Tl[512];
    __shared__ float sm[2];
    __shared__ float smc[2];
    __shared__ int mlist[512];
    __shared__ int mcnt;

    // zero Psum/Nsum(A,B)/scal (consumed by NEXT dispatches only)
    for (int i = b * 128 + d; i < nzero; i += B * 128) zbase[i] = 0.f;

    for (int i = d; i < B; i += 128) Tl[i] = T[i];
    if (d == 0) mcnt = 0;

    // cc |.| grid-strided partial (BW stream; 16 blocks/CU of TLP hides it)
    float cabs = 0.f;
    {
        const float4* cp = (const float4*)cc;
        const int n4 = C * 32;
        for (int i = b * 128 + d; i < n4; i += B * 128) {
            float4 v = cp[i];
            cabs += fabsf(v.x) + fabsf(v.y) + fabsf(v.z) + fabsf(v.w);
        }
    }
    #pragma unroll
    for (int off = 1; off < 64; off <<= 1) cabs += __shfl_xor(cabs, off);
    if ((d & 63) == 0) smc[d >> 6] = cabs;
    __syncthreads();                              // also covers Tl/mcnt init
    if (d == 0) cabs_part[b] = smc[0] + smc[1];

    const int c = Tl[b];

    // own row: normalize + swizzled bf16 store
    float x = X[(size_t)b * 128 + d];
    float n2 = bred128(x * x, sm, d);
    float xn = x * rsqrtf(n2 + 1e-12f);
    const int pk = ((((d >> 3) ^ (b & 15)) << 3) | (d & 7));   // swizzled column
    Xn16[(size_t)b * 128 + pk] = f2bf(xn);

    // parallel membership scan
    for (int j = d; j < B; j += 128)
        if (Tl[j] == c) mlist[atomicAdd(&mcnt, 1)] = j;
    __syncthreads();
    const int cnt = mcnt;
    int minj = mlist[0];
    for (int i = 1; i < cnt; ++i) minj = min(minj, mlist[i]);
    if (minj != b) return;                       // earlier block owns this class

    // member stats in ascending-j order (deterministic)
    float sd = 0.f, qd = 0.f;
    int prev = -1;
    for (int rank = 0; rank < cnt; ++rank) {
        int cur = 0x7fffffff;
        for (int i = 0; i < cnt; ++i) { int v = mlist[i]; if (v > prev && v < cur) cur = v; }
        prev = cur;
        float xj = X[(size_t)cur * 128 + d];
        float nj = bred128(xj * xj, sm, d);
        float xnj = xj * rsqrtf(nj + 1e-12f);
        sd += xnj; qd += xnj * xnj;
    }
    float fc = (float)cnt;
    float m = sd / fc;
    float var = fminf(fmaxf(qd / fc - m * m, 1e-6f), 10.0f);
    float sv = bred128(var, sm, d);

    float p  = proxies[(size_t)c * 128 + d];
    float cv = cc[(size_t)c * 128 + d];
    float s2 = bred128(p * p, sm, d);
    float c2 = bred128(cv * cv, sm, d);
    float pc = bred128(p * cv, sm, d);
    if (d == 0) {
        float inv = rsqrtf(s2 + 1e-12f);
        float pn = fmaxf(sqrtf(s2) * inv, COS_EPS);
        float cn = fmaxf(sqrtf(c2), COS_EPS);
        float censim = (pc * inv) / (pn * cn);
        float vw = 1.0f / (1.0f + sv * (1.0f / 128.0f));
        adj[c] = censim * vw * STAT_ADJ_W;
    }
}

// ---------------- K2: pure GEMM, 4-way row split (391 x 4) -------------------
// Each block: 128 classes x 128 rows, staged as 2 chunks x 16 KB (row-split
// keeps TOTAL staging at 50 MB — R3 lesson applies to class-splits only).
// Residency ~6 blocks/CU. Quarters {0,1} accumulate into buffer A, {2,3} into
// buffer B: exactly 2 commutative contributors per address -> deterministic.
// No cc scan, no fences, no finish logic — body is byte-identical otherwise.
__launch_bounds__(256, 2)
__global__ void k_main(const float* __restrict__ proxies, const ushort* __restrict__ Xsw,
                       const int* __restrict__ T, float* __restrict__ PN,
                       int C) {
    const int tid = threadIdx.x, lane = tid & 63, wv = tid >> 6;
    const int nlo = lane & 15, quad = lane >> 4;
    const int c0 = blockIdx.x * 128;
    const int q = blockIdx.y;                     // 0..3: which 128-row quarter
    const int r0 = q * 128;

    __shared__ ushort Sx[16384];      // 2 x 16 KB double buffer
    __shared__ alignas(16) int Tl[128];
    if (tid < 128) Tl[tid] = T[r0 + tid];

    // accumulation buffers: quarters {0,1} -> A, {2,3} -> B
    float* P = PN + (size_t)(q >> 1) * 2 * C;
    float* N = P + C;

    // ---- B fragments: 2 class-tiles, normalized in-register (proven shape) ----
    const int cls0 = c0 + wv * 32 + nlo;
    const int cls1 = cls0 + 16;
    bf16x8 bfr[2][4];
    #pragma unroll
    for (int t = 0; t < 2; ++t) {
        int cls = c0 + wv * 32 + t * 16 + nlo;
        int cl = (cls < C) ? cls : C - 1;
        const float4* pr = (const float4*)(proxies + (size_t)cl * 128);
        float4 v0[4], v1[4];
        float s2 = 0.f;
        #pragma unroll
        for (int ks = 0; ks < 4; ++ks) {
            v0[ks] = pr[ks * 8 + quad * 2];
            v1[ks] = pr[ks * 8 + quad * 2 + 1];
            s2 += v0[ks].x*v0[ks].x + v0[ks].y*v0[ks].y + v0[ks].z*v0[ks].z + v0[ks].w*v0[ks].w
                + v1[ks].x*v1[ks].x + v1[ks].y*v1[ks].y + v1[ks].z*v1[ks].z + v1[ks].w*v1[ks].w;
        }
        s2 += __shfl_xor(s2, 16);
        s2 += __shfl_xor(s2, 32);
        float pin = rsqrtf(s2 + 1e-12f);
        #pragma unroll
        for (int ks = 0; ks < 4; ++ks) {
            u32x4 u;
            u.x = pk2(v0[ks].x * pin, v0[ks].y * pin);
            u.y = pk2(v0[ks].z * pin, v0[ks].w * pin);
            u.z = pk2(v1[ks].x * pin, v1[ks].y * pin);
            u.w = pk2(v1[ks].z * pin, v1[ks].w * pin);
            bfr[t][ks] = __builtin_bit_cast(bf16x8, u);
        }
    }

    // ---- fragment LDS offsets; row low-4-bits == nlo so swizzle matches ----
    int fro[4];
    #pragma unroll
    for (int ks = 0; ks < 4; ++ks)
        fro[ks] = nlo * 128 + (((ks * 4 + quad) ^ nlo) << 3);

    // ---- staging pipeline: 2 chunks x 64 rows = 16 KB = 1024 uint4 each ----
    const uint4* gX = (const uint4*)Xsw + q * 2048;
    uint4 s0, s1, s2v, s3;
    #define LOADV(ch) { const uint4* p_ = gX + (ch) * 1024 + tid; \
                        s0 = p_[0]; s1 = p_[256]; s2v = p_[512]; s3 = p_[768]; }
    #define WRITEV(bi) { uint4* q_ = (uint4*)&Sx[(bi) * 8192]; \
                         q_[tid] = s0; q_[tid + 256] = s1; q_[tid + 512] = s2v; q_[tid + 768] = s3; }
    LOADV(0); WRITEV(0); LOADV(1);
    __syncthreads();

    float pp0 = 0.f, np0 = 0.f, pp1 = 0.f, np1 = 0.f;
    for (int chunk = 0; chunk < 2; ++chunk) {
        const int bo = chunk * 8192;
        if (chunk < 1) WRITEV(1);             // stage second chunk (regs ready)
        #pragma unroll
        for (int rt = 0; rt < 4; ++rt) {
            const ushort* sb = &Sx[bo + rt * 2048];
            bf16x8 a0 = *(const bf16x8*)&sb[fro[0]];
            bf16x8 a1 = *(const bf16x8*)&sb[fro[1]];
            bf16x8 a2 = *(const bf16x8*)&sb[fro[2]];
            bf16x8 a3 = *(const bf16x8*)&sb[fro[3]];
            f32x4 acc0 = {0.f,0.f,0.f,0.f}, acc1 = {0.f,0.f,0.f,0.f};
            acc0 = __builtin_amdgcn_mfma_f32_16x16x32_bf16(a0, bfr[0][0], acc0, 0, 0, 0);
            acc1 = __builtin_amdgcn_mfma_f32_16x16x32_bf16(a0, bfr[1][0], acc1, 0, 0, 0);
            acc0 = __builtin_amdgcn_mfma_f32_16x16x32_bf16(a1, bfr[0][1], acc0, 0, 0, 0);
            acc1 = __builtin_amdgcn_mfma_f32_16x16x32_bf16(a1, bfr[1][1], acc1, 0, 0, 0);
            acc0 = __builtin_amdgcn_mfma_f32_16x16x32_bf16(a2, bfr[0][2], acc0, 0, 0, 0);
            acc1 = __builtin_amdgcn_mfma_f32_16x16x32_bf16(a2, bfr[1][2], acc1, 0, 0, 0);
            acc0 = __builtin_amdgcn_mfma_f32_16x16x32_bf16(a3, bfr[0][3], acc0, 0, 0, 0);
            acc1 = __builtin_amdgcn_mfma_f32_16x16x32_bf16(a3, bfr[1][3], acc1, 0, 0, 0);

            int4 t4 = *(const int4*)&Tl[chunk * 64 + rt * 16 + quad * 4];
            int tvs[4] = {t4.x, t4.y, t4.z, t4.w};
            #pragma unroll
            for (int r = 0; r < 4; ++r) {
                { bool po = (tvs[r] == cls0); float v = acc0[r];
                  float e = __expf(po ? -ALPHA * (v - MRG) : ALPHA * (v + MRG));
                  pp0 += po ? e : 0.f; np0 += po ? 0.f : e; }
                { bool po = (tvs[r] == cls1); float v = acc1[r];
                  float e = __expf(po ? -ALPHA * (v - MRG) : ALPHA * (v + MRG));
                  pp1 += po ? e : 0.f; np1 += po ? 0.f : e; }
            }
        }
        __syncthreads();
    }
    #undef LOADV
    #undef WRITEV

    // ---- per-class quarter-totals across quads -> global atomics ----
    pp0 += __shfl_xor(pp0, 16); pp0 += __shfl_xor(pp0, 32);
    np0 += __shfl_xor(np0, 16); np0 += __shfl_xor(np0, 32);
    pp1 += __shfl_xor(pp1, 16); pp1 += __shfl_xor(pp1, 32);
    np1 += __shfl_xor(np1, 16); np1 += __shfl_xor(np1, 32);
    if (quad == 0) {
        if (cls0 < C) { atomicAdd(&P[cls0], pp0); atomicAdd(&N[cls0], np0); }
        if (cls1 < C) { atomicAdd(&P[cls1], pp1); atomicAdd(&N[cls1], np1); }
    }
}

// ---------------- K3: combine A+B, per-class log1p, final reduce -------------
__launch_bounds__(256)
__global__ void k_fin(const float* __restrict__ PN, const float* __restrict__ adj,
                      const float* __restrict__ cabs_part, float* __restrict__ scal,
                      float* __restrict__ out, int C, int nfin) {
    const int tid = threadIdx.x, lane = tid & 63, wv = tid >> 6;
    const int c = blockIdx.x * 256 + tid;
    __shared__ float red[4][3];
    float lp = 0.f, ln = 0.f, nv = 0.f;
    if (c < C) {
        float p = PN[c] + PN[2 * (size_t)C + c];           // A + B (fixed order)
        float n = PN[(size_t)C + c] + PN[3 * (size_t)C + c];
        float a = 0.f;
        if (p > 0.f) { a = adj[c]; nv = 1.f; }             // has_samples <=> p>0
        lp = log1pf(p * __expf(-ALPHA * a));
        ln = log1pf(n * __expf( ALPHA * a));
    }
    #pragma unroll
    for (int off = 1; off < 64; off <<= 1) {
        lp += __shfl_xor(lp, off);
        ln += __shfl_xor(ln, off);
        nv += __shfl_xor(nv, off);
    }
    if (lane == 0) { red[wv][0] = lp; red[wv][1] = ln; red[wv][2] = nv; }
    __syncthreads();
    if (tid == 0) {
        atomicAdd(&scal[0], red[0][0] + red[1][0] + red[2][0] + red[3][0]);
        atomicAdd(&scal[1], red[0][1] + red[1][1] + red[2][1] + red[3][1]);
        atomicAdd(&scal[3], red[0][2] + red[1][2] + red[2][2] + red[3][2]);
    }
    // block 0: cabs_part[512] sum -> scal[2]
    if (blockIdx.x == 0) {
        float cb = cabs_part[tid] + cabs_part[tid + 256];
        #pragma unroll
        for (int off = 1; off < 64; off <<= 1) cb += __shfl_xor(cb, off);
        __syncthreads();
        if (lane == 0) red[wv][0] = cb;
        __syncthreads();
        if (tid == 0) atomicAdd(&scal[2], red[0][0] + red[1][0] + red[2][0] + red[3][0]);
    }
    if (tid == 0) {
        __threadfence();
        unsigned old = atomicAdd((unsigned*)(scal + 4), 1u);
        if (old == (unsigned)(nfin - 1)) {       // last finisher assembles out
            float S0 = atomicAdd(&scal[0], 0.f);
            float S1 = atomicAdd(&scal[1], 0.f);
            float S2 = atomicAdd(&scal[2], 0.f);
            float S3 = atomicAdd(&scal[3], 0.f);
            out[0] = S0 / S3 + S1 / (float)C + STAT_WEIGHT * (S2 / ((float)C * 128.f));
        }
    }
}

extern "C" void kernel_launch(void* const* d_in, const int* in_sizes, int n_in,
                              void* d_out, int out_size, void* d_ws, size_t ws_size,
                              hipStream_t stream) {
    const float* X       = (const float*)d_in[0];
    const int*   T       = (const int*)d_in[1];
    const float* proxies = (const float*)d_in[2];
    const float* cc      = (const float*)d_in[3];
    float* out = (float*)d_out;

    const int B = in_sizes[1];            // 512
    const int D = in_sizes[0] / B;        // 128
    const int C = in_sizes[2] / D;        // 50000

    // workspace: [PA C][NA C][PB C][NB C][scal 8][cabs_part 512][adj C][Xn16]
    float*  PN   = (float*)d_ws;
    float*  scal = PN + 4 * (size_t)C;                 // 8
    float*  cabs_part = scal + 8;                      // 512
    float*  adj  = cabs_part + 512;                    // C
    ushort* Xn16 = (ushort*)(adj + C);                 // B*D bf16, swizzled

    const int nblk  = (C + 127) / 128;                 // 391
    const int nfin  = (C + 255) / 256;                 // 196
    const int nzero = 4 * C + 8;                       // PN + scal

    k_stats<<<B, 128, 0, stream>>>(X, proxies, cc, T, Xn16, adj, PN, nzero,
                                   cabs_part, C, B);
    k_main<<<dim3(nblk, 4), 256, 0, stream>>>(proxies, Xn16, T, PN, C);
    k_fin<<<nfin, 256, 0, stream>>>(PN, adj, cabs_part, scal, out, C, nfin);
}

// Round 8
// 130.638 us; speedup vs baseline: 1.2979x; 1.0091x over previous
//
#include <hip/hip_runtime.h>
#include <math.h>

#define ALPHA 32.0f
#define MRG 0.1f
#define STAT_WEIGHT 0.01f
#define STAT_ADJ_W 0.15f
#define COS_EPS 1e-8f

typedef __attribute__((ext_vector_type(8))) short bf16x8;
typedef __attribute__((ext_vector_type(4))) float f32x4;
typedef __attribute__((ext_vector_type(4))) unsigned int u32x4;

__device__ __forceinline__ ushort f2bf(float f) {
    unsigned u = __float_as_uint(f);
    return (ushort)((u + 0x7FFFu + ((u >> 16) & 1u)) >> 16);   // RNE
}
__device__ __forceinline__ unsigned pk2(float a, float b) {
    return (unsigned)f2bf(a) | ((unsigned)f2bf(b) << 16);
}

// block-wide (128 threads = 2 waves) sum reduce, result broadcast to all
__device__ __forceinline__ float bred128(float v, float* sm, int d) {
    #pragma unroll
    for (int off = 1; off < 64; off <<= 1) v += __shfl_xor(v, off);
    if ((d & 63) == 0) sm[d >> 6] = v;
    __syncthreads();
    float r = sm[0] + sm[1];
    __syncthreads();
    return r;
}

// ---------------- K1: scal zero + cc |.| scan + per-sample stats -------------
// (R7-proven body; zero loop shrunk to scal[8] — PN needs no zeroing anymore
// since k_main now does single-writer plain stores.)
__global__ void k_stats(const float* __restrict__ X, const float* __restrict__ proxies,
                        const float* __restrict__ cc, const int* __restrict__ T,
                        ushort* __restrict__ Xn16, float* __restrict__ adj,
                        float* __restrict__ scal, float* __restrict__ cabs_part,
                        int C, int B) {
    const int b = blockIdx.x, d = threadIdx.x;   // d in [0,128) == dim index
    __shared__ int Tl[512];
    __shared__ float sm[2];
    __shared__ float smc[2];
    __shared__ int mlist[512];
    __shared__ int mcnt;

    if (b == 0 && d < 8) scal[d] = 0.f;          // consumed by later dispatches

    for (int i = d; i < B; i += 128) Tl[i] = T[i];
    if (d == 0) mcnt = 0;

    // cc |.| grid-strided partial (BW stream; plain per-block store)
    float cabs = 0.f;
    {
        const float4* cp = (const float4*)cc;
        const int n4 = C * 32;
        for (int i = b * 128 + d; i < n4; i += B * 128) {
            float4 v = cp[i];
            cabs += fabsf(v.x) + fabsf(v.y) + fabsf(v.z) + fabsf(v.w);
        }
    }
    #pragma unroll
    for (int off = 1; off < 64; off <<= 1) cabs += __shfl_xor(cabs, off);
    if ((d & 63) == 0) smc[d >> 6] = cabs;
    __syncthreads();                              // also covers Tl/mcnt init
    if (d == 0) cabs_part[b] = smc[0] + smc[1];

    const int c = Tl[b];

    // own row: normalize + swizzled bf16 store
    float x = X[(size_t)b * 128 + d];
    float n2 = bred128(x * x, sm, d);
    float xn = x * rsqrtf(n2 + 1e-12f);
    const int pk = ((((d >> 3) ^ (b & 15)) << 3) | (d & 7));   // swizzled column
    Xn16[(size_t)b * 128 + pk] = f2bf(xn);

    // parallel membership scan
    for (int j = d; j < B; j += 128)
        if (Tl[j] == c) mlist[atomicAdd(&mcnt, 1)] = j;
    __syncthreads();
    const int cnt = mcnt;
    int minj = mlist[0];
    for (int i = 1; i < cnt; ++i) minj = min(minj, mlist[i]);
    if (minj != b) return;                       // earlier block owns this class

    // member stats in ascending-j order (deterministic)
    float sd = 0.f, qd = 0.f;
    int prev = -1;
    for (int rank = 0; rank < cnt; ++rank) {
        int cur = 0x7fffffff;
        for (int i = 0; i < cnt; ++i) { int v = mlist[i]; if (v > prev && v < cur) cur = v; }
        prev = cur;
        float xj = X[(size_t)cur * 128 + d];
        float nj = bred128(xj * xj, sm, d);
        float xnj = xj * rsqrtf(nj + 1e-12f);
        sd += xnj; qd += xnj * xnj;
    }
    float fc = (float)cnt;
    float m = sd / fc;
    float var = fminf(fmaxf(qd / fc - m * m, 1e-6f), 10.0f);
    float sv = bred128(var, sm, d);

    float p  = proxies[(size_t)c * 128 + d];
    float cv = cc[(size_t)c * 128 + d];
    float s2 = bred128(p * p, sm, d);
    float c2 = bred128(cv * cv, sm, d);
    float pc = bred128(p * cv, sm, d);
    if (d == 0) {
        float inv = rsqrtf(s2 + 1e-12f);
        float pn = fmaxf(sqrtf(s2) * inv, COS_EPS);
        float cn = fmaxf(sqrtf(c2), COS_EPS);
        float censim = (pc * inv) / (pn * cn);
        float vw = 1.0f / (1.0f + sv * (1.0f / 128.0f));
        adj[c] = censim * vw * STAT_ADJ_W;
    }
}

// ---------------- K2: persistent blocks, rows staged ONCE, barrier-free loop --
// Grid (256, 2) = 512 blocks = exactly 2/CU (LDS 66 KB). Block (i, h) stages
// its 256-row half of Xn16 into LDS ONCE (single barrier in the kernel), then
// strides over 128-class slices with NO barriers: each wave builds its 2 proxy
// fragments in-register and runs 16 rt iterations {4 ds_read + 8 MFMA + exp}.
// Each (class, half) has exactly ONE writer wave -> plain stores into PA/PB
// (no atomics, no zeroing); k_fin combines A+B in fixed order (deterministic).
__launch_bounds__(256, 2)
__global__ void k_main(const float* __restrict__ proxies, const ushort* __restrict__ Xsw,
                       const int* __restrict__ T, float* __restrict__ PN,
                       int C, int nslice) {
    const int tid = threadIdx.x, lane = tid & 63, wv = tid >> 6;
    const int nlo = lane & 15, quad = lane >> 4;
    const int half = blockIdx.y;                  // 0/1: which 256-row half

    __shared__ ushort Sx[32768];                  // 64 KB: 256 rows x 128 bf16
    __shared__ alignas(16) int Tl[256];

    // ---- stage all 256 rows once (layout-preserving contiguous copy) ----
    {
        const uint4* src = (const uint4*)Xsw + half * 4096;
        uint4* dst = (uint4*)Sx;
        #pragma unroll
        for (int k = 0; k < 16; ++k) dst[tid + k * 256] = src[tid + k * 256];
    }
    Tl[tid] = T[half * 256 + tid];
    __syncthreads();                              // the ONLY barrier

    float* PA = PN + (size_t)half * 2 * C;        // half0 -> A, half1 -> B
    float* NA = PA + C;

    // ---- fragment LDS offsets (in ushorts); swizzle index is nlo ----
    int fro[4];
    #pragma unroll
    for (int ks = 0; ks < 4; ++ks)
        fro[ks] = nlo * 128 + (((ks * 4 + quad) ^ nlo) << 3);

    for (int s = blockIdx.x; s < nslice; s += gridDim.x) {
        const int c0 = s * 128;
        const int cls0 = c0 + wv * 32 + nlo;
        const int cls1 = cls0 + 16;

        // B fragments: 2 class-tiles, normalized in-register (proven shape)
        bf16x8 bfr[2][4];
        #pragma unroll
        for (int t = 0; t < 2; ++t) {
            int cls = c0 + wv * 32 + t * 16 + nlo;
            int cl = (cls < C) ? cls : C - 1;
            const float4* pr = (const float4*)(proxies + (size_t)cl * 128);
            float4 v0[4], v1[4];
            float s2 = 0.f;
            #pragma unroll
            for (int ks = 0; ks < 4; ++ks) {
                v0[ks] = pr[ks * 8 + quad * 2];
                v1[ks] = pr[ks * 8 + quad * 2 + 1];
                s2 += v0[ks].x*v0[ks].x + v0[ks].y*v0[ks].y + v0[ks].z*v0[ks].z + v0[ks].w*v0[ks].w
                    + v1[ks].x*v1[ks].x + v1[ks].y*v1[ks].y + v1[ks].z*v1[ks].z + v1[ks].w*v1[ks].w;
            }
            s2 += __shfl_xor(s2, 16);
            s2 += __shfl_xor(s2, 32);
            float pin = rsqrtf(s2 + 1e-12f);
            #pragma unroll
            for (int ks = 0; ks < 4; ++ks) {
                u32x4 u;
                u.x = pk2(v0[ks].x * pin, v0[ks].y * pin);
                u.y = pk2(v0[ks].z * pin, v0[ks].w * pin);
                u.z = pk2(v1[ks].x * pin, v1[ks].y * pin);
                u.w = pk2(v1[ks].z * pin, v1[ks].w * pin);
                bfr[t][ks] = __builtin_bit_cast(bf16x8, u);
            }
        }

        float pp0 = 0.f, np0 = 0.f, pp1 = 0.f, np1 = 0.f;
        #pragma unroll 4
        for (int rt = 0; rt < 16; ++rt) {
            const ushort* sb = &Sx[rt * 2048];
            bf16x8 a0 = *(const bf16x8*)&sb[fro[0]];
            bf16x8 a1 = *(const bf16x8*)&sb[fro[1]];
            bf16x8 a2 = *(const bf16x8*)&sb[fro[2]];
            bf16x8 a3 = *(const bf16x8*)&sb[fro[3]];
            f32x4 acc0 = {0.f,0.f,0.f,0.f}, acc1 = {0.f,0.f,0.f,0.f};
            acc0 = __builtin_amdgcn_mfma_f32_16x16x32_bf16(a0, bfr[0][0], acc0, 0, 0, 0);
            acc1 = __builtin_amdgcn_mfma_f32_16x16x32_bf16(a0, bfr[1][0], acc1, 0, 0, 0);
            acc0 = __builtin_amdgcn_mfma_f32_16x16x32_bf16(a1, bfr[0][1], acc0, 0, 0, 0);
            acc1 = __builtin_amdgcn_mfma_f32_16x16x32_bf16(a1, bfr[1][1], acc1, 0, 0, 0);
            acc0 = __builtin_amdgcn_mfma_f32_16x16x32_bf16(a2, bfr[0][2], acc0, 0, 0, 0);
            acc1 = __builtin_amdgcn_mfma_f32_16x16x32_bf16(a2, bfr[1][2], acc1, 0, 0, 0);
            acc0 = __builtin_amdgcn_mfma_f32_16x16x32_bf16(a3, bfr[0][3], acc0, 0, 0, 0);
            acc1 = __builtin_amdgcn_mfma_f32_16x16x32_bf16(a3, bfr[1][3], acc1, 0, 0, 0);

            int4 t4 = *(const int4*)&Tl[rt * 16 + quad * 4];
            int tvs[4] = {t4.x, t4.y, t4.z, t4.w};
            #pragma unroll
            for (int r = 0; r < 4; ++r) {
                { bool po = (tvs[r] == cls0); float v = acc0[r];
                  float e = __expf(po ? -ALPHA * (v - MRG) : ALPHA * (v + MRG));
                  pp0 += po ? e : 0.f; np0 += po ? 0.f : e; }
                { bool po = (tvs[r] == cls1); float v = acc1[r];
                  float e = __expf(po ? -ALPHA * (v - MRG) : ALPHA * (v + MRG));
                  pp1 += po ? e : 0.f; np1 += po ? 0.f : e; }
            }
        }

        // per-class half-totals across quads -> PLAIN stores (single writer)
        pp0 += __shfl_xor(pp0, 16); pp0 += __shfl_xor(pp0, 32);
        np0 += __shfl_xor(np0, 16); np0 += __shfl_xor(np0, 32);
        pp1 += __shfl_xor(pp1, 16); pp1 += __shfl_xor(pp1, 32);
        np1 += __shfl_xor(np1, 16); np1 += __shfl_xor(np1, 32);
        if (quad == 0) {
            if (cls0 < C) { PA[cls0] = pp0; NA[cls0] = np0; }
            if (cls1 < C) { PA[cls1] = pp1; NA[cls1] = np1; }
        }
    }
}

// ---------------- K3: combine A+B, per-class log1p, final reduce -------------
__launch_bounds__(256)
__global__ void k_fin(const float* __restrict__ PN, const float* __restrict__ adj,
                      const float* __restrict__ cabs_part, float* __restrict__ scal,
                      float* __restrict__ out, int C, int nfin) {
    const int tid = threadIdx.x, lane = tid & 63, wv = tid >> 6;
    const int c = blockIdx.x * 256 + tid;
    __shared__ float red[4][3];
    float lp = 0.f, ln = 0.f, nv = 0.f;
    if (c < C) {
        float p = PN[c] + PN[2 * (size_t)C + c];           // A + B (fixed order)
        float n = PN[(size_t)C + c] + PN[3 * (size_t)C + c];
        float a = 0.f;
        if (p > 0.f) { a = adj[c]; nv = 1.f; }             // has_samples <=> p>0
        lp = log1pf(p * __expf(-ALPHA * a));
        ln = log1pf(n * __expf( ALPHA * a));
    }
    #pragma unroll
    for (int off = 1; off < 64; off <<= 1) {
        lp += __shfl_xor(lp, off);
        ln += __shfl_xor(ln, off);
        nv += __shfl_xor(nv, off);
    }
    if (lane == 0) { red[wv][0] = lp; red[wv][1] = ln; red[wv][2] = nv; }
    __syncthreads();
    if (tid == 0) {
        atomicAdd(&scal[0], red[0][0] + red[1][0] + red[2][0] + red[3][0]);
        atomicAdd(&scal[1], red[0][1] + red[1][1] + red[2][1] + red[3][1]);
        atomicAdd(&scal[3], red[0][2] + red[1][2] + red[2][2] + red[3][2]);
    }
    // block 0: cabs_part[512] sum -> scal[2]
    if (blockIdx.x == 0) {
        float cb = cabs_part[tid] + cabs_part[tid + 256];
        #pragma unroll
        for (int off = 1; off < 64; off <<= 1) cb += __shfl_xor(cb, off);
        __syncthreads();
        if (lane == 0) red[wv][0] = cb;
        __syncthreads();
        if (tid == 0) atomicAdd(&scal[2], red[0][0] + red[1][0] + red[2][0] + red[3][0]);
    }
    if (tid == 0) {
        __threadfence();
        unsigned old = atomicAdd((unsigned*)(scal + 4), 1u);
        if (old == (unsigned)(nfin - 1)) {       // last finisher assembles out
            float S0 = atomicAdd(&scal[0], 0.f);
            float S1 = atomicAdd(&scal[1], 0.f);
            float S2 = atomicAdd(&scal[2], 0.f);
            float S3 = atomicAdd(&scal[3], 0.f);
            out[0] = S0 / S3 + S1 / (float)C + STAT_WEIGHT * (S2 / ((float)C * 128.f));
        }
    }
}

extern "C" void kernel_launch(void* const* d_in, const int* in_sizes, int n_in,
                              void* d_out, int out_size, void* d_ws, size_t ws_size,
                              hipStream_t stream) {
    const float* X       = (const float*)d_in[0];
    const int*   T       = (const int*)d_in[1];
    const float* proxies = (const float*)d_in[2];
    const float* cc      = (const float*)d_in[3];
    float* out = (float*)d_out;

    const int B = in_sizes[1];            // 512
    const int D = in_sizes[0] / B;        // 128
    const int C = in_sizes[2] / D;        // 50000

    // workspace: [PA C][NA C][PB C][NB C][scal 8][cabs_part 512][adj C][Xn16]
    float*  PN   = (float*)d_ws;
    float*  scal = PN + 4 * (size_t)C;                 // 8
    float*  cabs_part = scal + 8;                      // 512
    float*  adj  = cabs_part + 512;                    // C
    ushort* Xn16 = (ushort*)(adj + C);                 // B*D bf16, swizzled

    const int nslice = (C + 127) / 128;                // 391
    const int nfin   = (C + 255) / 256;                // 196

    k_stats<<<B, 128, 0, stream>>>(X, proxies, cc, T, Xn16, adj, scal,
                                   cabs_part, C, B);
    k_main<<<dim3(256, 2), 256, 0, stream>>>(proxies, Xn16, T, PN, C, nslice);
    k_fin<<<nfin, 256, 0, stream>>>(PN, adj, cabs_part, scal, out, C, nfin);
}